// Round 10
// baseline (342.683 us; speedup 1.0000x reference)
//
#include <hip/hip_runtime.h>
#include <stdint.h>

typedef __attribute__((ext_vector_type(8))) short short8;
typedef __attribute__((ext_vector_type(4))) float f32x4;
typedef __attribute__((ext_vector_type(4))) int i32x4;
typedef __attribute__((ext_vector_type(4))) unsigned short usvec4;

static constexpr int T_ = 2048;
static constexpr int H_ = 768;
static constexpr int I_ = 3072;
static constexpr int RCAP = 6144;          // routed packed region (128-padded rows)
static constexpr int RT_ = RCAP + 2 * T_;  // 10240 total packed rows
static constexpr int BK_ = 32;

// ws byte offsets (weight regions unused now; xp/hact/etc. keep r9 offsets)
static constexpr long OFF_XP   = 141557760;
static constexpr long OFF_HACT = 157286400;
static constexpr long OFF_PART = 220200960;
static constexpr long OFF_META = 245366784;
static constexpr long OFF_TIDX = 245367040;
static constexpr long OFF_TW   = 245383424;
static constexpr long OFF_TOK  = 245399808;
static constexpr long OFF_SLOT = 245440768;
static constexpr long OFF_WL   = 245481728;

__device__ __forceinline__ unsigned short f2bf(float f) {
  union { float f; unsigned u; } v; v.f = f;
  unsigned r = (v.u + 0x7FFFu + ((v.u >> 16) & 1u)) >> 16;
  return (unsigned short)r;
}

__device__ __forceinline__ void gload_lds16(const void* g, void* l) {
  typedef const __attribute__((address_space(1))) void gvoid;
  typedef __attribute__((address_space(3))) void lvoid;
  gvoid* gp = (gvoid*)(uintptr_t)g;
  lvoid* lp = (lvoid*)(uint32_t)(uintptr_t)l;
  __builtin_amdgcn_global_load_lds(gp, lp, 16, 0, 0);
}

__device__ __forceinline__ f32x4 mfma16(short8 a, short8 b, f32x4 c) {
  return __builtin_amdgcn_mfma_f32_16x16x32_bf16(a, b, c, 0, 0, 0);
}

__device__ __forceinline__ short8 ds_read_b128_asm(unsigned int addr) {
  short8 v;
  asm volatile("ds_read_b128 %0, %1" : "=v"(v) : "v"(addr));
  return v;
}

__device__ __forceinline__ void wait_lgkm0_fence() {
  asm volatile("s_waitcnt lgkmcnt(0)" ::: "memory");
  __builtin_amdgcn_sched_barrier(0);  // rule 18: MFMA must not hoist above
}

// RNE f32 pair -> packed bf16 (identical rounding to f2bf)
__device__ __forceinline__ int cvtpk(float a, float b) {
  unsigned r;
  asm("v_cvt_pk_bf16_f32 %0, %1, %2" : "=v"(r) : "v"(a), "v"(b));
  return (int)r;
}
__device__ __forceinline__ i32x4 pk4(f32x4 a, f32x4 b) {
  i32x4 r;
  r[0] = cvtpk(a[0], a[1]); r[1] = cvtpk(a[2], a[3]);
  r[2] = cvtpk(b[0], b[1]); r[3] = cvtpk(b[2], b[3]);
  return r;
}

// involutive 16B-chunk swizzle within 256B groups (64B logical rows)
__device__ __forceinline__ unsigned swz(unsigned o) {
  return o ^ (((o >> 6) & 3u) << 4);
}

// ---------------- router: logits, softmax, top-2 -------------------------
__global__ void router_k(const float* __restrict__ x, const float* __restrict__ gw,
                         int* __restrict__ tidx, float* __restrict__ tw) {
  const int lane = threadIdx.x & 63;
  const int wv = threadIdx.x >> 6;
  const int t = blockIdx.x * 4 + wv;
  float xv[12];
  #pragma unroll
  for (int j = 0; j < 12; j++) xv[j] = x[(long)t * H_ + lane + j * 64];
  float lg[8];
  #pragma unroll
  for (int e = 0; e < 8; e++) {
    float s = 0.f;
    #pragma unroll
    for (int j = 0; j < 12; j++) s += xv[j] * gw[e * H_ + lane + j * 64];
    #pragma unroll
    for (int o = 32; o > 0; o >>= 1) s += __shfl_xor(s, o, 64);
    lg[e] = s;
  }
  if (lane == 0) {
    float m = lg[0];
    #pragma unroll
    for (int e = 1; e < 8; e++) m = fmaxf(m, lg[e]);
    float ex[8]; float S = 0.f;
    #pragma unroll
    for (int e = 0; e < 8; e++) { ex[e] = __expf(lg[e] - m); S += ex[e]; }
    int i0 = 0;
    #pragma unroll
    for (int e = 1; e < 8; e++) if (ex[e] > ex[i0]) i0 = e;
    int i1 = (i0 == 0) ? 1 : 0;
    #pragma unroll
    for (int e = 0; e < 8; e++) if (e != i0 && ex[e] > ex[i1]) i1 = e;
    float s0 = ex[i0] / S, s1 = ex[i1] / S;
    float den = s0 + s1 + 1e-8f;
    tidx[t * 2] = i0; tidx[t * 2 + 1] = i1;
    tw[t * 2] = s0 / den; tw[t * 2 + 1] = s1 / den;
  }
}

// ---------------- pack: per-expert row lists (128-padded) -----------------
__global__ void pack_k(const int* __restrict__ tidx, const float* __restrict__ tw,
                       int* __restrict__ meta, int* __restrict__ tokL,
                       int* __restrict__ slotL, float* __restrict__ wL) {
  __shared__ int cnt[8], base_s[8], cur[8];
  const int tid = threadIdx.x;
  if (tid < 8) { cnt[tid] = 0; cur[tid] = 0; }
  for (int r = tid; r < RT_; r += 1024) tokL[r] = -1;
  __syncthreads();
  for (int t = tid; t < T_; t += 1024) {
    atomicAdd(&cnt[tidx[t * 2]], 1);
    atomicAdd(&cnt[tidx[t * 2 + 1]], 1);
  }
  __syncthreads();
  if (tid == 0) {
    int run = 0;
    for (int e = 0; e < 8; e++) {
      base_s[e] = run;
      int pad = (cnt[e] + 127) & ~127;
      meta[e] = run;       // base row
      meta[10 + e] = pad;  // padded row count
      run += pad;
    }
    for (int s = 0; s < 2; s++) { meta[8 + s] = RCAP + s * T_; meta[18 + s] = T_; }
  }
  __syncthreads();
  for (int t = tid; t < T_; t += 1024) {
    for (int k = 0; k < 2; k++) {
      int e = tidx[t * 2 + k];
      int p = atomicAdd(&cur[e], 1);
      int R = base_s[e] + p;
      tokL[R] = t; slotL[R] = k; wL[R] = tw[t * 2 + k];
    }
    for (int s = 0; s < 2; s++) {
      int R = RCAP + s * T_ + t;
      tokL[R] = t; slotL[R] = 2 + s; wL[R] = 0.5f;
    }
  }
}

// ---------------- gather: packed bf16 activations, PRE-TILED --------------
__global__ void gather_k(const float* __restrict__ x, const int* __restrict__ tokL,
                         unsigned short* __restrict__ xp) {
  const int r = blockIdx.x, tid = threadIdx.x;  // 192 threads, 4 elems each
  const int tok = tokL[r];
  const int c = tid * 4;
  usvec4 o = 0;
  if (tok >= 0) {
    f32x4 v = *(const f32x4*)(x + (long)tok * H_ + c);
    #pragma unroll
    for (int j = 0; j < 4; j++) o[j] = f2bf(v[j]);
  }
  long dst = ((long)(r >> 7) * 24 + (c >> 5)) * 4096 + ((r & 127) << 5) + (c & 31);
  *(usvec4*)(xp + dst) = o;
}

// ---------------- GEMM1: fused gate+up + SwiGLU, fused fp32 weight cast ---
// A via global_load_lds (pre-tiled bf16 xp); G/U reg-staged fp32 -> cvt_pk ->
// ds_write. XCD-group remap keeps the fp32 weight panel in one XCD's L2.
__global__ __launch_bounds__(256, 2)
void gemm1_k(const unsigned short* __restrict__ xp,
             const float* __restrict__ rg, const float* __restrict__ ru,
             const float* __restrict__ sgw, const float* __restrict__ suw,
             const int* __restrict__ meta,
             unsigned short* __restrict__ hact) {
  const int fid = blockIdx.x;          // 0..3839 = 8 XCD x 30 gq x 16 bx
  const int xc  = fid & 7;
  const int q   = fid >> 3;
  const int bx  = q & 15;
  const int g   = (q >> 4) * 8 + xc;   // 0..239 ; XCD(fid)=fid%8=g%8
  const int e   = g / 24;
  const int by  = g % 24;

  const int rowsP = meta[10 + e];
  if (bx * 128 >= rowsP) return;
  const int base = meta[e];
  const int n0 = by * 128;

  const float* gw32; const float* uw32;
  if (e < 8) { gw32 = rg + (long)e * I_ * H_;        uw32 = ru + (long)e * I_ * H_; }
  else       { gw32 = sgw + (long)(e - 8) * I_ * H_; uw32 = suw + (long)(e - 8) * I_ * H_; }

  const int rblk = (base >> 7) + bx;
  const char* aT = (const char*)(xp + (long)rblk * 24 * 4096);  // +kk*8192 bytes

  __shared__ alignas(16) unsigned short As[3 * 4096];
  __shared__ alignas(16) unsigned short Bg[3 * 4096];
  __shared__ alignas(16) unsigned short Bu[3 * 4096];

  const int tid = threadIdx.x;
  const unsigned o1 = tid * 16, o2 = 4096 + tid * 16;
  const unsigned s1 = swz(o1), s2 = swz(o2);

  // weight staging: thread covers I-row wr, H-cols wh*16..+15 of each K-tile
  const int wr = tid >> 1, wh = tid & 1;
  const float* gRow = gw32 + (long)(n0 + wr) * H_ + wh * 16;
  const float* uRow = uw32 + (long)(n0 + wr) * H_ + wh * 16;
  const unsigned wo0 = (unsigned)(wr * 64 + wh * 32);
  const unsigned wd0 = swz(wo0), wd1 = swz(wo0 + 16);

  const int lane = tid & 63, wv = tid >> 6;
  const int wm = wv >> 1, wn = wv & 1;
  const int lm = lane & 15, ld = lane >> 4;
  int aOff[4], bOff[4];
  #pragma unroll
  for (int i = 0; i < 4; i++) {
    int ra = wm * 64 + i * 16 + lm;
    int rb = wn * 64 + i * 16 + lm;
    aOff[i] = ra * 64 + ((ld * 16) ^ ((ra & 3) << 4));
    bOff[i] = rb * 64 + ((ld * 16) ^ ((rb & 3) << 4));
  }
  const unsigned asBase = (unsigned)(uintptr_t)As;
  const unsigned bgBase = (unsigned)(uintptr_t)Bg;
  const unsigned buBase = (unsigned)(uintptr_t)Bu;

  f32x4 accG[4][4] = {};
  f32x4 accU[4][4] = {};
  f32x4 gS[4], uS[4];   // single fp32 staging set

  auto ADMA = [&](int kk) {
    const long ko = (long)kk * 8192;
    const unsigned bo = (unsigned)((kk % 3) * 8192);
    gload_lds16(aT + ko + s1, (char*)As + bo + o1);
    gload_lds16(aT + ko + s2, (char*)As + bo + o2);
  };
  auto LOADW = [&](int kk) {
    const float* gp = gRow + kk * 32;
    const float* up = uRow + kk * 32;
    #pragma unroll
    for (int j = 0; j < 4; j++) gS[j] = *(const f32x4*)(gp + j * 4);
    #pragma unroll
    for (int j = 0; j < 4; j++) uS[j] = *(const f32x4*)(up + j * 4);
  };
  auto CVTW = [&](int kk) {
    const unsigned bo = (unsigned)((kk % 3) * 8192);
    *(i32x4*)((char*)Bg + bo + wd0) = pk4(gS[0], gS[1]);
    *(i32x4*)((char*)Bg + bo + wd1) = pk4(gS[2], gS[3]);
    *(i32x4*)((char*)Bu + bo + wd0) = pk4(uS[0], uS[1]);
    *(i32x4*)((char*)Bu + bo + wd1) = pk4(uS[2], uS[3]);
  };
  auto COMP = [&](int kk) {
    const unsigned bo = (unsigned)((kk % 3) * 8192);
    short8 av[4], gv[4], uv[4];
    #pragma unroll
    for (int i = 0; i < 4; i++) {
      av[i] = ds_read_b128_asm(asBase + bo + aOff[i]);
      gv[i] = ds_read_b128_asm(bgBase + bo + bOff[i]);
      uv[i] = ds_read_b128_asm(buBase + bo + bOff[i]);
    }
    wait_lgkm0_fence();
    #pragma unroll
    for (int mi = 0; mi < 4; mi++)
      #pragma unroll
      for (int ni = 0; ni < 4; ni++) {
        accG[mi][ni] = mfma16(av[mi], gv[ni], accG[mi][ni]);
        accU[mi][ni] = mfma16(av[mi], uv[ni], accU[mi][ni]);
      }
  };

  constexpr int NK = H_ / BK_;  // 24
  ADMA(0); LOADW(0);
  asm volatile("s_waitcnt vmcnt(0)" ::: "memory");
  CVTW(0);
  ADMA(1); LOADW(1);
  asm volatile("s_waitcnt lgkmcnt(0)" ::: "memory");
  __builtin_amdgcn_s_barrier();
  __builtin_amdgcn_sched_barrier(0);

  for (int k = 0; k < NK; ++k) {
    if (k + 2 < NK) ADMA(k + 2);
    __builtin_amdgcn_sched_barrier(0);
    COMP(k);
    if (k + 1 < NK) {
      if (k + 2 < NK) asm volatile("s_waitcnt vmcnt(2)" ::: "memory");
      else            asm volatile("s_waitcnt vmcnt(0)" ::: "memory");
      CVTW(k + 1);                       // tile k+1 (loaded last iter) -> LDS
      if (k + 2 < NK) LOADW(k + 2);      // issue next loads; in flight over barrier
      asm volatile("s_waitcnt lgkmcnt(0)" ::: "memory");
      __builtin_amdgcn_s_barrier();
      __builtin_amdgcn_sched_barrier(0);
    } else {
      __builtin_amdgcn_s_barrier();
      __builtin_amdgcn_sched_barrier(0);
    }
  }

  // ---- epilogue: silu(g)*u -> LDS bounce -> short8 stores into TILED hact
  unsigned short* ep = (wv < 2) ? (As + wv * 2048) : (Bg + (wv - 2) * 2048);
  #pragma unroll
  for (int half = 0; half < 2; half++) {
    #pragma unroll
    for (int mi2 = 0; mi2 < 2; mi2++) {
      int mi = half * 2 + mi2;
      #pragma unroll
      for (int ni = 0; ni < 4; ni++) {
        f32x4 g2 = accG[mi][ni], u = accU[mi][ni];
        #pragma unroll
        for (int j = 0; j < 4; j++) {
          float gvv = g2[j];
          float hv = gvv / (1.0f + __expf(-gvv)) * u[j];
          ep[(mi2 * 16 + ld * 4 + j) * 64 + ni * 16 + lm] = f2bf(hv);
        }
      }
    }
    __syncthreads();
    #pragma unroll
    for (int it = 0; it < 4; it++) {
      int r = it * 8 + (lane >> 3);                 // 0..31 within half
      int c8 = (lane & 7) * 8;                      // 0..56
      short8 v = *(const short8*)(ep + r * 64 + c8);
      int R7 = wm * 64 + half * 32 + r;             // row & 127
      int C = n0 + wn * 64 + c8;                    // hcol
      long dst = ((long)rblk * 96 + (C >> 5)) * 4096 + (R7 << 5) + (C & 31);
      *(short8*)(hact + dst) = v;
    }
    __syncthreads();
  }
}

// ---------------- GEMM2: down proj + weighted scatter, fused fp32 cast ----
__global__ __launch_bounds__(256, 3)
void gemm2_k(const unsigned short* __restrict__ hact,
             const float* __restrict__ rd, const float* __restrict__ sd,
             const int* __restrict__ meta,
             const int* __restrict__ tokL,
             const int* __restrict__ slotL,
             const float* __restrict__ wLst,
             float* __restrict__ parts) {
  const int fid = blockIdx.x;          // 0..1023 = 8 XCD x 8 gq x 16 bx
  const int xc  = fid & 7;
  const int q   = fid >> 3;
  const int bx  = q & 15;
  const int g   = (q >> 4) * 8 + xc;   // 0..63
  if (g >= 60) return;
  const int e   = g / 6;
  const int by  = g % 6;

  const int rowsP = meta[10 + e];
  if (bx * 128 >= rowsP) return;
  const int base = meta[e];
  const int n0 = by * 128;
  const float* dw32 = (e < 8) ? rd + (long)e * H_ * I_
                              : sd + (long)(e - 8) * H_ * I_;
  const int rblk = (base >> 7) + bx;
  const char* aT = (const char*)(hact + (long)rblk * 96 * 4096);

  __shared__ alignas(16) unsigned short As[3 * 4096];
  __shared__ alignas(16) unsigned short Bd[3 * 4096];
  const int tid = threadIdx.x;
  const unsigned o1 = tid * 16, o2 = 4096 + tid * 16;
  const unsigned s1 = swz(o1), s2 = swz(o2);

  const int wr = tid >> 1, wh = tid & 1;
  const float* dRow = dw32 + (long)(n0 + wr) * I_ + wh * 16;
  const unsigned wo0 = (unsigned)(wr * 64 + wh * 32);
  const unsigned wd0 = swz(wo0), wd1 = swz(wo0 + 16);

  const int lane = tid & 63, wv = tid >> 6;
  const int wm = wv >> 1, wn = wv & 1;
  const int lm = lane & 15, ld = lane >> 4;
  int aOff[4], bOff[4];
  #pragma unroll
  for (int i = 0; i < 4; i++) {
    int ra = wm * 64 + i * 16 + lm;
    int rb = wn * 64 + i * 16 + lm;
    aOff[i] = ra * 64 + ((ld * 16) ^ ((ra & 3) << 4));
    bOff[i] = rb * 64 + ((ld * 16) ^ ((rb & 3) << 4));
  }
  const unsigned asBase = (unsigned)(uintptr_t)As;
  const unsigned bdBase = (unsigned)(uintptr_t)Bd;
  f32x4 acc[4][4] = {};
  f32x4 dS[4];   // single fp32 staging set

  auto ADMA = [&](int kk) {
    const long ko = (long)kk * 8192;
    const unsigned bo = (unsigned)((kk % 3) * 8192);
    gload_lds16(aT + ko + s1, (char*)As + bo + o1);
    gload_lds16(aT + ko + s2, (char*)As + bo + o2);
  };
  auto LOADW = [&](int kk) {
    const float* dp = dRow + kk * 32;
    #pragma unroll
    for (int j = 0; j < 4; j++) dS[j] = *(const f32x4*)(dp + j * 4);
  };
  auto CVTW = [&](int kk) {
    const unsigned bo = (unsigned)((kk % 3) * 8192);
    *(i32x4*)((char*)Bd + bo + wd0) = pk4(dS[0], dS[1]);
    *(i32x4*)((char*)Bd + bo + wd1) = pk4(dS[2], dS[3]);
  };
  auto COMP = [&](int kk) {
    const unsigned bo = (unsigned)((kk % 3) * 8192);
    short8 av[4], bv[4];
    #pragma unroll
    for (int i = 0; i < 4; i++) {
      av[i] = ds_read_b128_asm(asBase + bo + aOff[i]);
      bv[i] = ds_read_b128_asm(bdBase + bo + bOff[i]);
    }
    wait_lgkm0_fence();
    #pragma unroll
    for (int mi = 0; mi < 4; mi++)
      #pragma unroll
      for (int ni = 0; ni < 4; ni++)
        acc[mi][ni] = mfma16(av[mi], bv[ni], acc[mi][ni]);
  };

  constexpr int NK = I_ / BK_;  // 96
  ADMA(0); LOADW(0);
  asm volatile("s_waitcnt vmcnt(0)" ::: "memory");
  CVTW(0);
  ADMA(1); LOADW(1);
  asm volatile("s_waitcnt lgkmcnt(0)" ::: "memory");
  __builtin_amdgcn_s_barrier();
  __builtin_amdgcn_sched_barrier(0);

  for (int k = 0; k < NK; ++k) {
    if (k + 2 < NK) ADMA(k + 2);
    __builtin_amdgcn_sched_barrier(0);
    COMP(k);
    if (k + 1 < NK) {
      if (k + 2 < NK) asm volatile("s_waitcnt vmcnt(2)" ::: "memory");
      else            asm volatile("s_waitcnt vmcnt(0)" ::: "memory");
      CVTW(k + 1);
      if (k + 2 < NK) LOADW(k + 2);
      asm volatile("s_waitcnt lgkmcnt(0)" ::: "memory");
      __builtin_amdgcn_s_barrier();
      __builtin_amdgcn_sched_barrier(0);
    } else {
      __builtin_amdgcn_s_barrier();
      __builtin_amdgcn_sched_barrier(0);
    }
  }

  const long R0 = base + bx * 128 + wm * 64;
  #pragma unroll
  for (int mi = 0; mi < 4; mi++) {
    #pragma unroll
    for (int j = 0; j < 4; j++) {
      long R = R0 + mi * 16 + ld * 4 + j;
      int tok = tokL[R];
      if (tok < 0) continue;
      float w = wLst[R];
      long obase = (long)slotL[R] * (T_ * H_) + (long)tok * H_ + n0 + wn * 64 + lm;
      #pragma unroll
      for (int ni = 0; ni < 4; ni++) {
        parts[obase + ni * 16] = w * acc[mi][ni][j];
      }
    }
  }
}

// ---------------- final: sum 4 slot partials ------------------------------
__global__ void final_k(const float* __restrict__ parts, float* __restrict__ out) {
  const int i = blockIdx.x * 256 + threadIdx.x;
  const int N4 = T_ * H_ / 4;
  const f32x4* p = (const f32x4*)parts;
  f32x4 s = p[i];
  s += p[N4 + i];
  s += p[2 * N4 + i];
  s += p[3 * N4 + i];
  ((f32x4*)out)[i] = s;
}

extern "C" void kernel_launch(void* const* d_in, const int* in_sizes, int n_in,
                              void* d_out, int out_size, void* d_ws, size_t ws_size,
                              hipStream_t stream) {
  (void)in_sizes; (void)n_in; (void)out_size; (void)ws_size;
  const float* x  = (const float*)d_in[0];
  const float* gw = (const float*)d_in[1];
  const float* sg = (const float*)d_in[2];
  const float* su = (const float*)d_in[3];
  const float* sd = (const float*)d_in[4];
  const float* rg = (const float*)d_in[5];
  const float* ru = (const float*)d_in[6];
  const float* rd = (const float*)d_in[7];

  char* ws = (char*)d_ws;
  unsigned short* xp   = (unsigned short*)(ws + OFF_XP);
  unsigned short* ha   = (unsigned short*)(ws + OFF_HACT);
  float*          prt  = (float*)(ws + OFF_PART);
  int*            meta = (int*)(ws + OFF_META);
  int*            tidx = (int*)(ws + OFF_TIDX);
  float*          tw   = (float*)(ws + OFF_TW);
  int*            tokL = (int*)(ws + OFF_TOK);
  int*            slotL= (int*)(ws + OFF_SLOT);
  float*          wl   = (float*)(ws + OFF_WL);

  router_k<<<512, 256, 0, stream>>>(x, gw, tidx, tw);
  pack_k<<<1, 1024, 0, stream>>>(tidx, tw, meta, tokL, slotL, wl);
  gather_k<<<RT_, 192, 0, stream>>>(x, tokL, xp);
  gemm1_k<<<3840, 256, 0, stream>>>(xp, rg, ru, sg, su, meta, ha);
  gemm2_k<<<1024, 256, 0, stream>>>(ha, rd, sd, meta, tokL, slotL, wl, prt);
  final_k<<<1536, 256, 0, stream>>>(prt, (float*)d_out);
}

// Round 11
// 276.038 us; speedup vs baseline: 1.2414x; 1.2414x over previous
//
#include <hip/hip_runtime.h>
#include <stdint.h>

typedef __attribute__((ext_vector_type(8))) short short8;
typedef __attribute__((ext_vector_type(4))) float f32x4;
typedef __attribute__((ext_vector_type(4))) unsigned short usvec4;

static constexpr int T_ = 2048;
static constexpr int H_ = 768;
static constexpr int I_ = 3072;
static constexpr int RCAP = 6144;          // routed packed region (128-padded rows)
static constexpr int RT_ = RCAP + 2 * T_;  // 10240 total packed rows
static constexpr int TILE_ = 128;
static constexpr int BK_ = 32;

// bf16 weight region offsets in ws (ushort element units)
static constexpr long WE_SG = 0;
static constexpr long WE_SU = 4718592;
static constexpr long WE_SD = 9437184;
static constexpr long WE_RG = 14155776;
static constexpr long WE_RU = 33030144;
static constexpr long WE_RD = 51904512;
// byte offsets
static constexpr long OFF_XP   = 141557760;
static constexpr long OFF_HACT = 157286400;
static constexpr long OFF_PART = 220200960;
static constexpr long OFF_META = 245366784;
static constexpr long OFF_TIDX = 245367040;
static constexpr long OFF_TW   = 245383424;
static constexpr long OFF_TOK  = 245399808;
static constexpr long OFF_SLOT = 245440768;
static constexpr long OFF_WL   = 245481728;

__device__ __forceinline__ unsigned short f2bf(float f) {
  union { float f; unsigned u; } v; v.f = f;
  unsigned r = (v.u + 0x7FFFu + ((v.u >> 16) & 1u)) >> 16;
  return (unsigned short)r;
}

__device__ __forceinline__ void gload_lds16(const void* g, void* l) {
  typedef const __attribute__((address_space(1))) void gvoid;
  typedef __attribute__((address_space(3))) void lvoid;
  gvoid* gp = (gvoid*)(uintptr_t)g;
  lvoid* lp = (lvoid*)(uint32_t)(uintptr_t)l;
  __builtin_amdgcn_global_load_lds(gp, lp, 16, 0, 0);
}

__device__ __forceinline__ f32x4 mfma16(short8 a, short8 b, f32x4 c) {
  return __builtin_amdgcn_mfma_f32_16x16x32_bf16(a, b, c, 0, 0, 0);
}

__device__ __forceinline__ short8 ds_read_b128_asm(unsigned int addr) {
  short8 v;
  asm volatile("ds_read_b128 %0, %1" : "=v"(v) : "v"(addr));
  return v;
}

__device__ __forceinline__ void wait_lgkm0_fence() {
  asm volatile("s_waitcnt lgkmcnt(0)" ::: "memory");
  __builtin_amdgcn_sched_barrier(0);  // rule 18: MFMA must not hoist above
}
__device__ __forceinline__ void wait_vmcnt_barrier6(bool counted) {
  if (counted) asm volatile("s_waitcnt vmcnt(6)" ::: "memory");
  else         asm volatile("s_waitcnt vmcnt(0)" ::: "memory");
  __builtin_amdgcn_s_barrier();
  __builtin_amdgcn_sched_barrier(0);
}
__device__ __forceinline__ void wait_vmcnt_barrier4(bool counted) {
  if (counted) asm volatile("s_waitcnt vmcnt(4)" ::: "memory");
  else         asm volatile("s_waitcnt vmcnt(0)" ::: "memory");
  __builtin_amdgcn_s_barrier();
  __builtin_amdgcn_sched_barrier(0);
}

// involutive 16B-chunk swizzle within 64B rows, keyed on row bits 1-2:
// read slot = (row&1 bank-half, chunk ^ ((row>>1)&3)) -> 16 rows span all
// 8 slots -> 2-way aliasing only (free), vs 4-way with (row&3).
__device__ __forceinline__ unsigned swz(unsigned o) {
  return o ^ (((o >> 7) & 3u) << 4);
}

// ---------------- cast weights fp32 -> bf16, PRE-TILED --------------------
// G/U-type (src [E][I][H]):  tile = [(i>>7)*24 + (h>>5)]*4096 + (i&127)*32 + (h&31)
// D-type  (src [E][H][I]):   tile = [(h>>7)*96 + (i>>5)]*4096 + (h&127)*32 + (i&31)
__global__ void cast_weights_k(const float* __restrict__ sg, const float* __restrict__ su,
                               const float* __restrict__ sd, const float* __restrict__ rg,
                               const float* __restrict__ ru, const float* __restrict__ rd,
                               unsigned short* __restrict__ wb) {
  long c = (long)blockIdx.x * 256 + threadIdx.x;  // 4-elem chunks, 17694720 total
  const float* src; long dstoff, lc; int dtype = 0;
  if      (c <  1179648) { src = sg; dstoff = WE_SG; lc = c; }
  else if (c <  2359296) { src = su; dstoff = WE_SU; lc = c - 1179648; }
  else if (c <  3538944) { src = sd; dstoff = WE_SD; lc = c - 2359296; dtype = 1; }
  else if (c <  8257536) { src = rg; dstoff = WE_RG; lc = c - 3538944; }
  else if (c < 12976128) { src = ru; dstoff = WE_RU; lc = c - 8257536; }
  else                   { src = rd; dstoff = WE_RD; lc = c - 12976128; dtype = 1; }
  f32x4 a = ((const f32x4*)src)[lc];
  usvec4 o;
  #pragma unroll
  for (int j = 0; j < 4; j++) o[j] = f2bf(a[j]);
  constexpr long EW = (long)I_ * H_;
  long f = lc * 4;
  long e = f / EW; f -= e * EW;
  long dst;
  if (dtype == 0) {
    int i = (int)(f / H_), h = (int)(f - (long)i * H_);
    dst = dstoff + e * EW + ((long)((i >> 7) * 24 + (h >> 5))) * 4096 + ((i & 127) << 5) + (h & 31);
  } else {
    int h = (int)(f / I_), i = (int)(f - (long)h * I_);
    dst = dstoff + e * EW + ((long)((h >> 7) * 96 + (i >> 5))) * 4096 + ((h & 127) << 5) + (i & 31);
  }
  *(usvec4*)(wb + dst) = o;
}

// ---------------- router: logits, softmax, top-2 -------------------------
__global__ void router_k(const float* __restrict__ x, const float* __restrict__ gw,
                         int* __restrict__ tidx, float* __restrict__ tw) {
  const int lane = threadIdx.x & 63;
  const int wv = threadIdx.x >> 6;
  const int t = blockIdx.x * 4 + wv;
  float xv[12];
  #pragma unroll
  for (int j = 0; j < 12; j++) xv[j] = x[(long)t * H_ + lane + j * 64];
  float lg[8];
  #pragma unroll
  for (int e = 0; e < 8; e++) {
    float s = 0.f;
    #pragma unroll
    for (int j = 0; j < 12; j++) s += xv[j] * gw[e * H_ + lane + j * 64];
    #pragma unroll
    for (int o = 32; o > 0; o >>= 1) s += __shfl_xor(s, o, 64);
    lg[e] = s;
  }
  if (lane == 0) {
    float m = lg[0];
    #pragma unroll
    for (int e = 1; e < 8; e++) m = fmaxf(m, lg[e]);
    float ex[8]; float S = 0.f;
    #pragma unroll
    for (int e = 0; e < 8; e++) { ex[e] = __expf(lg[e] - m); S += ex[e]; }
    int i0 = 0;
    #pragma unroll
    for (int e = 1; e < 8; e++) if (ex[e] > ex[i0]) i0 = e;
    int i1 = (i0 == 0) ? 1 : 0;
    #pragma unroll
    for (int e = 0; e < 8; e++) if (e != i0 && ex[e] > ex[i1]) i1 = e;
    float s0 = ex[i0] / S, s1 = ex[i1] / S;
    float den = s0 + s1 + 1e-8f;
    tidx[t * 2] = i0; tidx[t * 2 + 1] = i1;
    tw[t * 2] = s0 / den; tw[t * 2 + 1] = s1 / den;
  }
}

// ---------------- pack: per-expert row lists (128-padded) -----------------
__global__ void pack_k(const int* __restrict__ tidx, const float* __restrict__ tw,
                       int* __restrict__ meta, int* __restrict__ tokL,
                       int* __restrict__ slotL, float* __restrict__ wL) {
  __shared__ int cnt[8], base_s[8], cur[8];
  const int tid = threadIdx.x;
  if (tid < 8) { cnt[tid] = 0; cur[tid] = 0; }
  for (int r = tid; r < RT_; r += 1024) tokL[r] = -1;
  __syncthreads();
  for (int t = tid; t < T_; t += 1024) {
    atomicAdd(&cnt[tidx[t * 2]], 1);
    atomicAdd(&cnt[tidx[t * 2 + 1]], 1);
  }
  __syncthreads();
  if (tid == 0) {
    int run = 0;
    for (int e = 0; e < 8; e++) {
      base_s[e] = run;
      int pad = (cnt[e] + 127) & ~127;
      meta[e] = run;       // base row
      meta[10 + e] = pad;  // padded row count
      run += pad;
    }
    for (int s = 0; s < 2; s++) { meta[8 + s] = RCAP + s * T_; meta[18 + s] = T_; }
  }
  __syncthreads();
  for (int t = tid; t < T_; t += 1024) {
    for (int k = 0; k < 2; k++) {
      int e = tidx[t * 2 + k];
      int p = atomicAdd(&cur[e], 1);
      int R = base_s[e] + p;
      tokL[R] = t; slotL[R] = k; wL[R] = tw[t * 2 + k];
    }
    for (int s = 0; s < 2; s++) {
      int R = RCAP + s * T_ + t;
      tokL[R] = t; slotL[R] = 2 + s; wL[R] = 0.5f;
    }
  }
}

// ---------------- gather: packed bf16 activations, PRE-TILED --------------
__global__ void gather_k(const float* __restrict__ x, const int* __restrict__ tokL,
                         unsigned short* __restrict__ xp) {
  const int r = blockIdx.x, tid = threadIdx.x;  // 192 threads, 4 elems each
  const int tok = tokL[r];
  const int c = tid * 4;
  usvec4 o = 0;
  if (tok >= 0) {
    f32x4 v = *(const f32x4*)(x + (long)tok * H_ + c);
    #pragma unroll
    for (int j = 0; j < 4; j++) o[j] = f2bf(v[j]);
  }
  long dst = ((long)(r >> 7) * 24 + (c >> 5)) * 4096 + ((r & 127) << 5) + (c & 31);
  *(usvec4*)(xp + dst) = o;
}

// ---------------- GEMM1: fused gate+up + SwiGLU -----------------------
// Contiguous staging + XCD-group remap (r9) + 2-way-only LDS swizzle.
__global__ __launch_bounds__(256, 2)
void gemm1_k(const unsigned short* __restrict__ xp,
             const unsigned short* __restrict__ wb,
             const int* __restrict__ meta,
             unsigned short* __restrict__ hact) {
  const int fid = blockIdx.x;          // 0..3839 = 8 XCD x 30 gq x 16 bx
  const int x   = fid & 7;
  const int q   = fid >> 3;
  const int bx  = q & 15;
  const int g   = (q >> 4) * 8 + x;    // 0..239 ; XCD(fid)=fid%8=g%8
  const int e   = g / 24;
  const int by  = g % 24;

  const int rowsP = meta[10 + e];
  if (bx * TILE_ >= rowsP) return;
  const int base = meta[e];
  const int n0 = by * TILE_;

  const unsigned short* gwp;
  const unsigned short* uwp;
  if (e < 8) { gwp = wb + WE_RG + (long)e * I_ * H_;       uwp = wb + WE_RU + (long)e * I_ * H_; }
  else       { gwp = wb + WE_SG + (long)(e - 8) * I_ * H_; uwp = wb + WE_SU + (long)(e - 8) * I_ * H_; }

  const int rblk = (base >> 7) + bx;
  const char* aT = (const char*)(xp + (long)rblk * 24 * 4096);   // +kk*8192 bytes
  const char* gT = (const char*)(gwp + (long)by * 24 * 4096);
  const char* uT = (const char*)(uwp + (long)by * 24 * 4096);

  __shared__ alignas(16) unsigned short As[3 * TILE_ * BK_];
  __shared__ alignas(16) unsigned short Bg[3 * TILE_ * BK_];
  __shared__ alignas(16) unsigned short Bu[3 * TILE_ * BK_];

  const int tid = threadIdx.x;
  const unsigned o1 = tid * 16, o2 = 4096 + tid * 16;
  const unsigned s1 = swz(o1), s2 = swz(o2);

  const int lane = tid & 63, wv = tid >> 6;
  const int wm = wv >> 1, wn = wv & 1;
  const int lm = lane & 15, ld = lane >> 4;

  // fragment LDS offsets (swizzled): row*64B + (ld*16 ^ (((row>>1)&3)<<4))
  int aOff[4], bOff[4];
  #pragma unroll
  for (int i = 0; i < 4; i++) {
    int ra = wm * 64 + i * 16 + lm;
    int rb = wn * 64 + i * 16 + lm;
    aOff[i] = ra * 64 + ((ld * 16) ^ (((ra >> 1) & 3) << 4));
    bOff[i] = rb * 64 + ((ld * 16) ^ (((rb >> 1) & 3) << 4));
  }
  const unsigned asBase = (unsigned)(uintptr_t)As;
  const unsigned bgBase = (unsigned)(uintptr_t)Bg;
  const unsigned buBase = (unsigned)(uintptr_t)Bu;

  f32x4 accG[4][4] = {};
  f32x4 accU[4][4] = {};

  auto stage = [&](int buf, int kk) {
    const long ko = (long)kk * 8192;
    const unsigned bo = buf * 8192;
    gload_lds16(aT + ko + s1, (char*)As + bo + o1);
    gload_lds16(aT + ko + s2, (char*)As + bo + o2);
    gload_lds16(gT + ko + s1, (char*)Bg + bo + o1);
    gload_lds16(gT + ko + s2, (char*)Bg + bo + o2);
    gload_lds16(uT + ko + s1, (char*)Bu + bo + o1);
    gload_lds16(uT + ko + s2, (char*)Bu + bo + o2);
  };

  constexpr int NK = H_ / BK_;  // 24
  stage(0, 0);
  stage(1, 1);
  asm volatile("s_waitcnt vmcnt(6)" ::: "memory");
  __builtin_amdgcn_s_barrier();
  __builtin_amdgcn_sched_barrier(0);

  for (int kk = 0; kk < NK; ++kk) {
    const int cur = kk % 3;
    const bool more = (kk + 2 < NK);
    if (more) stage((kk + 2) % 3, kk + 2);
    const unsigned bo = cur * 8192;
    short8 av[4], gv[4], uv[4];
    #pragma unroll
    for (int i = 0; i < 4; i++) {
      av[i] = ds_read_b128_asm(asBase + bo + aOff[i]);
      gv[i] = ds_read_b128_asm(bgBase + bo + bOff[i]);
      uv[i] = ds_read_b128_asm(buBase + bo + bOff[i]);
    }
    wait_lgkm0_fence();
    #pragma unroll
    for (int mi = 0; mi < 4; mi++)
      #pragma unroll
      for (int ni = 0; ni < 4; ni++) {
        accG[mi][ni] = mfma16(av[mi], gv[ni], accG[mi][ni]);
        accU[mi][ni] = mfma16(av[mi], uv[ni], accU[mi][ni]);
      }
    wait_vmcnt_barrier6(more);
  }

  // ---- epilogue: silu(g)*u -> LDS bounce -> short8 stores into TILED hact
  unsigned short* ep = (wv < 2) ? (As + wv * 2048) : (Bg + (wv - 2) * 2048);
  #pragma unroll
  for (int half = 0; half < 2; half++) {
    #pragma unroll
    for (int mi2 = 0; mi2 < 2; mi2++) {
      int mi = half * 2 + mi2;
      #pragma unroll
      for (int ni = 0; ni < 4; ni++) {
        f32x4 g2 = accG[mi][ni], u = accU[mi][ni];
        #pragma unroll
        for (int j = 0; j < 4; j++) {
          float gvv = g2[j];
          float hv = gvv / (1.0f + __expf(-gvv)) * u[j];
          ep[(mi2 * 16 + ld * 4 + j) * 64 + ni * 16 + lm] = f2bf(hv);
        }
      }
    }
    __syncthreads();
    #pragma unroll
    for (int it = 0; it < 4; it++) {
      int r = it * 8 + (lane >> 3);                 // 0..31 within half
      int c8 = (lane & 7) * 8;                      // 0..56
      short8 v = *(const short8*)(ep + r * 64 + c8);
      int R7 = wm * 64 + half * 32 + r;             // row & 127
      int C = n0 + wn * 64 + c8;                    // hcol
      long dst = ((long)rblk * 96 + (C >> 5)) * 4096 + (R7 << 5) + (C & 31);
      *(short8*)(hact + dst) = v;
    }
    __syncthreads();
  }
}

// ---------------- GEMM2: down proj + weighted scatter ---------------------
__global__ __launch_bounds__(256, 3)
void gemm2_k(const unsigned short* __restrict__ hact,
             const unsigned short* __restrict__ wb,
             const int* __restrict__ meta,
             const int* __restrict__ tokL,
             const int* __restrict__ slotL,
             const float* __restrict__ wLst,
             float* __restrict__ parts) {
  const int fid = blockIdx.x;          // 0..1023 = 8 XCD x 8 gq x 16 bx
  const int x   = fid & 7;
  const int q   = fid >> 3;
  const int bx  = q & 15;
  const int g   = (q >> 4) * 8 + x;    // 0..63
  if (g >= 60) return;
  const int e   = g / 6;
  const int by  = g % 6;

  const int rowsP = meta[10 + e];
  if (bx * TILE_ >= rowsP) return;
  const int base = meta[e];
  const int n0 = by * TILE_;
  const unsigned short* dwp = (e < 8) ? wb + WE_RD + (long)e * H_ * I_
                                      : wb + WE_SD + (long)(e - 8) * H_ * I_;
  const int rblk = (base >> 7) + bx;
  const char* aT = (const char*)(hact + (long)rblk * 96 * 4096);
  const char* bT = (const char*)(dwp + (long)by * 96 * 4096);

  __shared__ alignas(16) unsigned short As[3 * TILE_ * BK_];
  __shared__ alignas(16) unsigned short Bd[3 * TILE_ * BK_];
  const int tid = threadIdx.x;
  const unsigned o1 = tid * 16, o2 = 4096 + tid * 16;
  const unsigned s1 = swz(o1), s2 = swz(o2);
  const int lane = tid & 63, wv = tid >> 6;
  const int wm = wv >> 1, wn = wv & 1;
  const int lm = lane & 15, ld = lane >> 4;
  int aOff[4], bOff[4];
  #pragma unroll
  for (int i = 0; i < 4; i++) {
    int ra = wm * 64 + i * 16 + lm;
    int rb = wn * 64 + i * 16 + lm;
    aOff[i] = ra * 64 + ((ld * 16) ^ (((ra >> 1) & 3) << 4));
    bOff[i] = rb * 64 + ((ld * 16) ^ (((rb >> 1) & 3) << 4));
  }
  const unsigned asBase = (unsigned)(uintptr_t)As;
  const unsigned bdBase = (unsigned)(uintptr_t)Bd;
  f32x4 acc[4][4] = {};

  auto stage = [&](int buf, int kk) {
    const long ko = (long)kk * 8192;
    const unsigned bo = buf * 8192;
    gload_lds16(aT + ko + s1, (char*)As + bo + o1);
    gload_lds16(aT + ko + s2, (char*)As + bo + o2);
    gload_lds16(bT + ko + s1, (char*)Bd + bo + o1);
    gload_lds16(bT + ko + s2, (char*)Bd + bo + o2);
  };

  constexpr int NK = I_ / BK_;  // 96
  stage(0, 0);
  stage(1, 1);
  asm volatile("s_waitcnt vmcnt(4)" ::: "memory");
  __builtin_amdgcn_s_barrier();
  __builtin_amdgcn_sched_barrier(0);

  for (int kk = 0; kk < NK; ++kk) {
    const int cur = kk % 3;
    const bool more = (kk + 2 < NK);
    if (more) stage((kk + 2) % 3, kk + 2);
    const unsigned bo = cur * 8192;
    short8 av[4], bv[4];
    #pragma unroll
    for (int i = 0; i < 4; i++) {
      av[i] = ds_read_b128_asm(asBase + bo + aOff[i]);
      bv[i] = ds_read_b128_asm(bdBase + bo + bOff[i]);
    }
    wait_lgkm0_fence();
    #pragma unroll
    for (int mi = 0; mi < 4; mi++)
      #pragma unroll
      for (int ni = 0; ni < 4; ni++)
        acc[mi][ni] = mfma16(av[mi], bv[ni], acc[mi][ni]);
    wait_vmcnt_barrier4(more);
  }

  const long R0 = base + bx * TILE_ + wm * 64;
  #pragma unroll
  for (int mi = 0; mi < 4; mi++) {
    #pragma unroll
    for (int j = 0; j < 4; j++) {
      long R = R0 + mi * 16 + ld * 4 + j;
      int tok = tokL[R];
      if (tok < 0) continue;
      float w = wLst[R];
      long obase = (long)slotL[R] * (T_ * H_) + (long)tok * H_ + n0 + wn * 64 + lm;
      #pragma unroll
      for (int ni = 0; ni < 4; ni++) {
        parts[obase + ni * 16] = w * acc[mi][ni][j];
      }
    }
  }
}

// ---------------- final: sum 4 slot partials ------------------------------
__global__ void final_k(const float* __restrict__ parts, float* __restrict__ out) {
  const int i = blockIdx.x * 256 + threadIdx.x;
  const int N4 = T_ * H_ / 4;
  const f32x4* p = (const f32x4*)parts;
  f32x4 s = p[i];
  s += p[N4 + i];
  s += p[2 * N4 + i];
  s += p[3 * N4 + i];
  ((f32x4*)out)[i] = s;
}

extern "C" void kernel_launch(void* const* d_in, const int* in_sizes, int n_in,
                              void* d_out, int out_size, void* d_ws, size_t ws_size,
                              hipStream_t stream) {
  (void)in_sizes; (void)n_in; (void)out_size; (void)ws_size;
  const float* x  = (const float*)d_in[0];
  const float* gw = (const float*)d_in[1];
  const float* sg = (const float*)d_in[2];
  const float* su = (const float*)d_in[3];
  const float* sd = (const float*)d_in[4];
  const float* rg = (const float*)d_in[5];
  const float* ru = (const float*)d_in[6];
  const float* rd = (const float*)d_in[7];

  char* ws = (char*)d_ws;
  unsigned short* wb   = (unsigned short*)ws;
  unsigned short* xp   = (unsigned short*)(ws + OFF_XP);
  unsigned short* ha   = (unsigned short*)(ws + OFF_HACT);
  float*          prt  = (float*)(ws + OFF_PART);
  int*            meta = (int*)(ws + OFF_META);
  int*            tidx = (int*)(ws + OFF_TIDX);
  float*          tw   = (float*)(ws + OFF_TW);
  int*            tokL = (int*)(ws + OFF_TOK);
  int*            slotL= (int*)(ws + OFF_SLOT);
  float*          wl   = (float*)(ws + OFF_WL);

  cast_weights_k<<<69120, 256, 0, stream>>>(sg, su, sd, rg, ru, rd, wb);
  router_k<<<512, 256, 0, stream>>>(x, gw, tidx, tw);
  pack_k<<<1, 1024, 0, stream>>>(tidx, tw, meta, tokL, slotL, wl);
  gather_k<<<RT_, 192, 0, stream>>>(x, tokL, xp);
  gemm1_k<<<3840, 256, 0, stream>>>(xp, wb, meta, ha);
  gemm2_k<<<1024, 256, 0, stream>>>(ha, wb, meta, tokL, slotL, wl, prt);
  final_k<<<1536, 256, 0, stream>>>(prt, (float*)d_out);
}